// Round 3
// baseline (7980.649 us; speedup 1.0000x reference)
//
#include <hip/hip_runtime.h>
#include <cstdint>
#include <cstddef>

// Problem constants
constexpr int B_ = 32;
constexpr int L_ = 512;
constexpr int D_ = 2048;
constexpr int T_ = 20;
constexpr int V_ = 10000;
constexpr int G_ = 4 * D_;        // 8192 gate rows
constexpr int KC_ = 32;           // K chunk staged in LDS
constexpr int JT_ = 128;          // J tile per block
constexpr int JPADO_ = 10112;     // 79*128, padded J for Wo partials

__device__ __forceinline__ float sigmoidf_(float x) { return 1.0f / (1.0f + expf(-x)); }

// ---------------------------------------------------------------------------
// GEMM: part[seg][j][b] = sum_{k in seg} sum_{p<npair} Wp[j,k] * Xp_T[k][b]
// W: row-major [J][K]. X_T: [K][B_] (b-minor). Output partial, b-minor.
// Per-wave 32j x 32b tile, per-lane 4x4 accumulators.
// ---------------------------------------------------------------------------
__global__ __launch_bounds__(256, 2) void gemm_nt(
    const float* __restrict__ W0, const float* __restrict__ X0,
    const float* __restrict__ W1, const float* __restrict__ X1,
    float* __restrict__ part, int Jpad, int Jreal, int K, int ksegK, int npair)
{
  __shared__ __align__(16) float Ws[KC_][132];  // [k][j], pad 132: 4-way only on writes
  __shared__ __align__(16) float Xs[KC_][36];   // [k][b]
  const int jt = blockIdx.x, seg = blockIdx.y;
  const int t = threadIdx.x;
  const int wave = t >> 6, lane = t & 63;
  const int jg = lane >> 3, bg = lane & 7;
  const int j0 = jt * JT_;
  const int jc = wave * 32 + jg * 4;   // j offset within tile
  const int bc = bg * 4;               // b offset
  const int kseg0 = seg * ksegK;

  float acc[4][4];
  #pragma unroll
  for (int i = 0; i < 4; ++i)
    #pragma unroll
    for (int q = 0; q < 4; ++q) acc[i][q] = 0.0f;

  for (int p = 0; p < npair; ++p) {
    const float* __restrict__ Wp = p ? W1 : W0;
    const float* __restrict__ Xp = p ? X1 : X0;
    for (int kc = 0; kc < ksegK; kc += KC_) {
      const int kbase = kseg0 + kc;
      __syncthreads();
      {  // stage X chunk: 32k x 32b
        const int kk = t >> 3, bq = (t & 7) * 4;
        const float4 xv = *reinterpret_cast<const float4*>(Xp + (size_t)(kbase + kk) * B_ + bq);
        *reinterpret_cast<float4*>(&Xs[kk][bq]) = xv;
      }
      #pragma unroll
      for (int pass = 0; pass < 4; ++pass) {  // stage W chunk transposed: 128j x 32k
        const int jl = pass * 32 + (t >> 3);
        const int u = (t & 7) * 4;
        float4 wv = make_float4(0.f, 0.f, 0.f, 0.f);
        const int jgl = j0 + jl;
        if (jgl < Jreal)
          wv = *reinterpret_cast<const float4*>(Wp + (size_t)jgl * K + kbase + u);
        Ws[u + 0][jl] = wv.x;
        Ws[u + 1][jl] = wv.y;
        Ws[u + 2][jl] = wv.z;
        Ws[u + 3][jl] = wv.w;
      }
      __syncthreads();
      #pragma unroll
      for (int k = 0; k < KC_; ++k) {  // k uniform per wave -> conflict-free b128 reads
        const float4 wv = *reinterpret_cast<const float4*>(&Ws[k][jc]);
        const float4 xv = *reinterpret_cast<const float4*>(&Xs[k][bc]);
        const float w[4] = {wv.x, wv.y, wv.z, wv.w};
        const float x[4] = {xv.x, xv.y, xv.z, xv.w};
        #pragma unroll
        for (int i = 0; i < 4; ++i)
          #pragma unroll
          for (int q = 0; q < 4; ++q)
            acc[i][q] += w[i] * x[q];
      }
    }
  }
  #pragma unroll
  for (int i = 0; i < 4; ++i) {
    const int j = j0 + jc + i;
    if (j < Jreal) {
      float4 o = make_float4(acc[i][0], acc[i][1], acc[i][2], acc[i][3]);
      *reinterpret_cast<float4*>(part + ((size_t)seg * Jpad + j) * B_ + bc) = o;
    }
  }
}

// ---------------------------------------------------------------------------
// LSTM cell epilogue: sum partials + biases, apply gates, in-place h/c update.
// ---------------------------------------------------------------------------
__global__ __launch_bounds__(256) void lstm_cell(
    const float* __restrict__ part, int nseg,
    const float* __restrict__ b_ih, const float* __restrict__ b_hh,
    float* __restrict__ h_T, float* __restrict__ c_T)
{
  const int t = threadIdx.x;
  const int d = blockIdx.x * 8 + (t >> 5);
  const int b = t & 31;
  float g[4];
  #pragma unroll
  for (int gi = 0; gi < 4; ++gi) {
    const int j = gi * D_ + d;
    float s = b_ih[j] + b_hh[j];
    for (int sg = 0; sg < nseg; ++sg)
      s += part[((size_t)sg * G_ + j) * B_ + b];
    g[gi] = s;
  }
  const float iv = sigmoidf_(g[0]);
  const float fv = sigmoidf_(g[1]);
  const float gv = tanhf(g[2]);
  const float ov = sigmoidf_(g[3]);
  const size_t o = (size_t)d * B_ + b;
  const float c = fv * c_T[o] + iv * gv;
  const float h = ov * tanhf(c);
  c_T[o] = c;
  h_T[o] = h;
}

// ---------------------------------------------------------------------------
// h1 = c1 = mean_l features[b,l,:]
// ---------------------------------------------------------------------------
__global__ __launch_bounds__(256) void mean_features(
    const float* __restrict__ feat, float* __restrict__ h1_T, float* __restrict__ c1_T)
{
  const int b = blockIdx.x, dt = blockIdx.y, t = threadIdx.x;
  const int d = dt * 256 + t;
  const float* fp = feat + (size_t)b * L_ * D_ + d;
  float s = 0.0f;
  #pragma unroll 4
  for (int l = 0; l < L_; ++l) s += fp[(size_t)l * D_];
  s *= (1.0f / L_);
  h1_T[(size_t)d * B_ + b] = s;
  c1_T[(size_t)d * B_ + b] = s;
}

// transpose [B][D] inputs into [D][B] working layout (h2_init, c2_init)
__global__ __launch_bounds__(256) void transpose_bd(
    const float* __restrict__ h2i, const float* __restrict__ c2i,
    float* __restrict__ h2_T, float* __restrict__ c2_T)
{
  const int b = blockIdx.x, dt = blockIdx.y, t = threadIdx.x;
  const int d = dt * 256 + t;
  h2_T[(size_t)d * B_ + b] = h2i[(size_t)b * D_ + d];
  c2_T[(size_t)d * B_ + b] = c2i[(size_t)b * D_ + d];
}

// x_T[:,b] = embed[captions[b,0],:]
__global__ __launch_bounds__(512) void gather_x0(
    const int* __restrict__ captions, const float* __restrict__ embed, float* __restrict__ x_T)
{
  const int b = blockIdx.x, t = threadIdx.x;
  const int cap = captions[b * T_];
  const float* ep = embed + (size_t)cap * D_;
  for (int d = t; d < D_; d += 512) x_T[(size_t)d * B_ + b] = ep[d];
}

// argmax over out[b, tstep, :] (first-max tie-break) then gather embed row
__global__ __launch_bounds__(512) void argmax_gather(
    const float* __restrict__ out, int tstep, const float* __restrict__ embed,
    float* __restrict__ x_T)
{
  const int b = blockIdx.x, t = threadIdx.x;
  const int lane = t & 63, wave = t >> 6;
  const float* op = out + ((size_t)b * T_ + tstep) * V_;
  float bv = -3.4e38f; int bi = 0;
  for (int v = t; v < V_; v += 512) {
    const float val = op[v];
    if (val > bv) { bv = val; bi = v; }   // ascending scan -> keeps smallest idx on tie
  }
  #pragma unroll
  for (int o = 32; o; o >>= 1) {
    const float ov = __shfl_xor(bv, o);
    const int oi = __shfl_xor(bi, o);
    if (ov > bv || (ov == bv && oi < bi)) { bv = ov; bi = oi; }
  }
  __shared__ float rv[8]; __shared__ int ri[8];
  if (lane == 0) { rv[wave] = bv; ri[wave] = bi; }
  __syncthreads();
  float fv = rv[0]; int fi = ri[0];
  #pragma unroll
  for (int i = 1; i < 8; ++i)
    if (rv[i] > fv || (rv[i] == fv && ri[i] < fi)) { fv = rv[i]; fi = ri[i]; }
  const float* ep = embed + (size_t)fi * D_;
  for (int d = t; d < D_; d += 512) x_T[(size_t)d * B_ + b] = ep[d];
}

// logits[b,l] = dot(h2[:,b], features[b,l,:]) — wave per l
__global__ __launch_bounds__(256) void attn_logits(
    const float* __restrict__ feat, const float* __restrict__ h2_T, float* __restrict__ logits)
{
  const int b = blockIdx.x, lt = blockIdx.y, t = threadIdx.x;
  __shared__ __align__(16) float h2s[D_];
  for (int i = t; i < D_; i += 256) h2s[i] = h2_T[(size_t)i * B_ + b];
  __syncthreads();
  const int wave = t >> 6, lane = t & 63;
  for (int li = 0; li < 16; ++li) {
    const int l = lt * 64 + wave * 16 + li;
    const float* fp = feat + ((size_t)b * L_ + l) * D_;
    float s = 0.0f;
    #pragma unroll
    for (int i = 0; i < 8; ++i) {
      const float4 f4 = *reinterpret_cast<const float4*>(fp + lane * 4 + i * 256);
      const float4 h4 = *reinterpret_cast<const float4*>(&h2s[lane * 4 + i * 256]);
      s += f4.x * h4.x + f4.y * h4.y + f4.z * h4.z + f4.w * h4.w;
    }
    #pragma unroll
    for (int o = 32; o; o >>= 1) s += __shfl_down(s, o);
    if (lane == 0) logits[b * L_ + l] = s;
  }
}

// context_T[d][b] = sum_l softmax(logits[b,:])[l] * features[b,l,d]
// softmax recomputed per block from logits (512 loads + exps — negligible
// vs this block's 1 MB feature stream); removes a kernel + alpha round-trip.
__global__ __launch_bounds__(256) void attn_context(
    const float* __restrict__ feat, const float* __restrict__ logits, float* __restrict__ ctx_T)
{
  const int b = blockIdx.x, dt = blockIdx.y, t = threadIdx.x;
  const int lane = t & 63, wave = t >> 6;
  __shared__ float a_s[L_];
  __shared__ float red[8];
  const float v0 = logits[b * L_ + t];
  const float v1 = logits[b * L_ + t + 256];
  float m = fmaxf(v0, v1);
  #pragma unroll
  for (int o = 32; o; o >>= 1) m = fmaxf(m, __shfl_xor(m, o));
  if (lane == 0) red[wave] = m;
  __syncthreads();
  float bm = fmaxf(fmaxf(red[0], red[1]), fmaxf(red[2], red[3]));
  const float e0 = expf(v0 - bm);
  const float e1 = expf(v1 - bm);
  float s = e0 + e1;
  #pragma unroll
  for (int o = 32; o; o >>= 1) s += __shfl_xor(s, o);
  __syncthreads();               // red reuse
  if (lane == 0) red[wave] = s;
  __syncthreads();
  const float bs = (red[0] + red[1]) + (red[2] + red[3]);
  const float inv = 1.0f / bs;
  a_s[t] = e0 * inv;
  a_s[t + 256] = e1 * inv;
  __syncthreads();
  const int d = dt * 256 + t;
  const float* fp = feat + (size_t)b * L_ * D_ + d;
  float acc = 0.0f;
  #pragma unroll 4
  for (int l = 0; l < L_; ++l) acc += a_s[l] * fp[(size_t)l * D_];
  ctx_T[(size_t)d * B_ + b] = acc;
}

// S_T = sum partials (Wc@ctx + Wh@h2) + bc + bh + embed[idx] (== x_T)
__global__ __launch_bounds__(256) void s_epilogue(
    const float* __restrict__ part, int nseg,
    const float* __restrict__ bc, const float* __restrict__ bh,
    const float* __restrict__ x_T, float* __restrict__ S_T)
{
  const int t = threadIdx.x;
  const int d = blockIdx.x * 8 + (t >> 5);
  const int b = t & 31;
  const size_t o = (size_t)d * B_ + b;
  float s = bc[d] + bh[d] + x_T[o];
  for (int sg = 0; sg < nseg; ++sg)
    s += part[((size_t)sg * D_ + d) * B_ + b];
  S_T[o] = s;
}

// out[b, tstep, v] = sum_seg partO[seg][v][b] + bo[v]; LDS transpose for coalesced writes
__global__ __launch_bounds__(256) void out_epilogue(
    const float* __restrict__ part, int nseg,
    const float* __restrict__ bo, float* __restrict__ out, int tstep)
{
  __shared__ float tile[256 * 33];
  const int vt = blockIdx.x, t = threadIdx.x;
  const int vl = t >> 5, b = t & 31;
  #pragma unroll 4
  for (int i = 0; i < 32; ++i) {
    const int vloc = i * 8 + vl;
    const int v = vt * 256 + vloc;
    float s = 0.0f;
    if (v < V_) {
      s = bo[v];
      for (int sg = 0; sg < nseg; ++sg)
        s += part[((size_t)sg * JPADO_ + v) * B_ + b];
    }
    tile[vloc * 33 + b] = s;
  }
  __syncthreads();
  const int b2 = t >> 3, vq = t & 7;
  #pragma unroll
  for (int r = 0; r < 8; ++r) {
    const int vloc = r * 32 + vq * 4;
    const int v = vt * 256 + vloc;
    if (v < V_) {   // V_%4==0 so v<V_ implies v+3<V_
      const float4 o4 = make_float4(tile[(vloc + 0) * 33 + b2], tile[(vloc + 1) * 33 + b2],
                                    tile[(vloc + 2) * 33 + b2], tile[(vloc + 3) * 33 + b2]);
      *reinterpret_cast<float4*>(out + ((size_t)b2 * T_ + tstep) * V_ + v) = o4;
    }
  }
}

// ---------------------------------------------------------------------------
extern "C" void kernel_launch(void* const* d_in, const int* in_sizes, int n_in,
                              void* d_out, int out_size, void* d_ws, size_t ws_size,
                              hipStream_t stream) {
  const float* feat  = (const float*)d_in[0];
  const int*   caps  = (const int*)d_in[1];
  const float* h2i   = (const float*)d_in[2];
  const float* c2i   = (const float*)d_in[3];
  const float* embed = (const float*)d_in[4];
  const float* W_ih1 = (const float*)d_in[5];
  const float* W_hh1 = (const float*)d_in[6];
  const float* b_ih1 = (const float*)d_in[7];
  const float* b_hh1 = (const float*)d_in[8];
  const float* W_ih2 = (const float*)d_in[9];
  const float* W_hh2 = (const float*)d_in[10];
  const float* b_ih2 = (const float*)d_in[11];
  const float* b_hh2 = (const float*)d_in[12];
  const float* Wc    = (const float*)d_in[13];
  const float* bc    = (const float*)d_in[14];
  const float* Wh    = (const float*)d_in[15];
  const float* bh    = (const float*)d_in[16];
  const float* Wo    = (const float*)d_in[17];
  const float* bo    = (const float*)d_in[18];
  float* out = (float*)d_out;

  float* ws = (float*)d_ws;
  // workspace layout (floats)
  float* part   = ws;                                  // max 8*10112*32 = 2,588,672
  float* h1     = part + 2588672;
  float* c1     = h1 + D_ * B_;
  float* h2     = c1 + D_ * B_;
  float* c2     = h2 + D_ * B_;
  float* xg     = c2 + D_ * B_;                        // embed[idx], [D][B]
  float* ctx    = xg + D_ * B_;
  float* St     = ctx + D_ * B_;
  float* logits = St + D_ * B_;

  // ---- initial step (t = 0) ----
  mean_features<<<dim3(32, 8), 256, 0, stream>>>(feat, h1, c1);
  gather_x0<<<32, 512, 0, stream>>>(caps, embed, xg);
  transpose_bd<<<dim3(32, 8), 256, 0, stream>>>(h2i, c2i, h2, c2);
  gemm_nt<<<dim3(64, 8), 256, 0, stream>>>(W_ih1, xg, W_hh1, h1, part, G_, G_, D_, 256, 2);
  lstm_cell<<<256, 256, 0, stream>>>(part, 8, b_ih1, b_hh1, h1, c1);
  gemm_nt<<<dim3(64, 8), 256, 0, stream>>>(W_ih2, h1, W_hh2, h2, part, G_, G_, D_, 256, 2);
  lstm_cell<<<256, 256, 0, stream>>>(part, 8, b_ih2, b_hh2, h2, c2);
  gemm_nt<<<dim3(79, 8), 256, 0, stream>>>(Wo, h2, nullptr, nullptr, part, JPADO_, V_, D_, 256, 1);
  out_epilogue<<<40, 256, 0, stream>>>(part, 8, bo, out, 0);

  // ---- steps 1..19 ----
  for (int ts = 1; ts < T_; ++ts) {
    argmax_gather<<<32, 512, 0, stream>>>(out, ts - 1, embed, xg);
    gemm_nt<<<dim3(64, 8), 256, 0, stream>>>(W_ih1, xg, W_hh1, h1, part, G_, G_, D_, 256, 2);
    lstm_cell<<<256, 256, 0, stream>>>(part, 8, b_ih1, b_hh1, h1, c1);
    gemm_nt<<<dim3(64, 8), 256, 0, stream>>>(W_ih2, h1, W_hh2, h2, part, G_, G_, D_, 256, 2);
    lstm_cell<<<256, 256, 0, stream>>>(part, 8, b_ih2, b_hh2, h2, c2);
    attn_logits<<<dim3(32, 8), 256, 0, stream>>>(feat, h2, logits);
    attn_context<<<dim3(32, 8), 256, 0, stream>>>(feat, logits, ctx);
    gemm_nt<<<dim3(16, 16), 256, 0, stream>>>(Wc, ctx, Wh, h2, part, D_, D_, D_, 128, 2);
    s_epilogue<<<256, 256, 0, stream>>>(part, 16, bc, bh, xg, St);
    gemm_nt<<<dim3(79, 8), 256, 0, stream>>>(Wo, St, nullptr, nullptr, part, JPADO_, V_, D_, 256, 1);
    out_epilogue<<<40, 256, 0, stream>>>(part, 8, bo, out, ts);
  }
}